// Round 1
// baseline (737.091 us; speedup 1.0000x reference)
//
#include <hip/hip_runtime.h>
#include <cstdint>
#include <cstddef>

// ---------------------------------------------------------------------------
// Fused attention layer, MI355X/gfx950, round 1 (correctness-first bf16 MFMA)
//   q = query@Wq+bq ; k = key@Wk+bk ; v = value@Wv+bv   (bf16 MFMA GEMMs)
//   attn = softmax(q kT / 8) v                           (flash, per-wave)
//   out  = attn@Wo + bo                                  (fp32 store)
// Constants: B=4, T=S=2048, D=1024, H=16, hd=64, M=B*T=8192
// ---------------------------------------------------------------------------

typedef __bf16 bf16x8 __attribute__((ext_vector_type(8)));
typedef float  f32x4  __attribute__((ext_vector_type(4)));
typedef unsigned short ushort_t;

#define DEV __device__ __forceinline__

DEV ushort_t f2bf(float f) {                 // RNE fp32 -> bf16 bits
  unsigned int u = __builtin_bit_cast(unsigned int, f);
  u = u + 0x7fffu + ((u >> 16) & 1u);
  return (ushort_t)(u >> 16);
}
DEV float bf2f(ushort_t b) {
  unsigned int u = ((unsigned int)b) << 16;
  return __builtin_bit_cast(float, u);
}
DEV bf16x8 ld16(const ushort_t* p) { return *(const bf16x8*)p; }

DEV void gload_lds16(const void* g, void* l) {
  // async global->LDS, 16B/lane; LDS dest is wave-uniform-base + lane*16
  __builtin_amdgcn_global_load_lds(
      (__attribute__((address_space(1))) void*)(void*)g,
      (__attribute__((address_space(3))) void*)l, 16, 0, 0);
}

// ---------------------------------------------------------------------------
// fp32 -> bf16 elementwise convert (vectorized)
// ---------------------------------------------------------------------------
__global__ void cvt_kernel(const float* __restrict__ in, ushort_t* __restrict__ out, int n4) {
  int i = blockIdx.x * blockDim.x + threadIdx.x;
  const int stride = gridDim.x * blockDim.x;
  for (; i < n4; i += stride) {
    const float4 v = ((const float4*)in)[i];
    ushort4 o;
    o.x = f2bf(v.x); o.y = f2bf(v.y); o.z = f2bf(v.z); o.w = f2bf(v.w);
    ((ushort4*)out)[i] = o;
  }
}

// ---------------------------------------------------------------------------
// W[k][n] fp32 -> Wt[n][k] bf16 (tiled transpose, 1024x1024)
// ---------------------------------------------------------------------------
__global__ void transpose_cvt_kernel(const float* __restrict__ W, ushort_t* __restrict__ Wt) {
  __shared__ float tile[32][33];
  const int c0 = blockIdx.x * 32, r0 = blockIdx.y * 32;
  const int x = threadIdx.x, y0 = threadIdx.y;
#pragma unroll
  for (int yy = 0; yy < 32; yy += 8)
    tile[y0 + yy][x] = W[(size_t)(r0 + y0 + yy) * 1024 + c0 + x];
  __syncthreads();
#pragma unroll
  for (int yy = 0; yy < 32; yy += 8)
    Wt[(size_t)(c0 + y0 + yy) * 1024 + r0 + x] = f2bf(tile[x][y0 + yy]);
}

// ---------------------------------------------------------------------------
// bf16 GEMM: C[M=8192][N=1024] = A[M][K=1024] @ W[K][N] + bias, W given as
// Wt[n][k]. 128x128 tile, BK=32, 4 waves x (64x64), global_load_lds staging.
// OUTMODE: 0 = bf16 row-major, 1 = bf16 transposed into Vt[b][h][64][2048],
//          2 = fp32 row-major (final output)
// ---------------------------------------------------------------------------
template <int OUTMODE>
__global__ __launch_bounds__(256)
void gemm_kernel(const ushort_t* __restrict__ A, const ushort_t* __restrict__ Bt,
                 const float* __restrict__ bias, void* __restrict__ Cout) {
  constexpr int K = 1024, N = 1024;
  __shared__ __attribute__((aligned(16))) ushort_t As[128 * 32];
  __shared__ __attribute__((aligned(16))) ushort_t Bs[128 * 32];
  const int tid = threadIdx.x;
  const int l = tid & 63, w = tid >> 6;
  const int l15 = l & 15, lg = l >> 4;
  const int bm = blockIdx.x >> 3, bn = blockIdx.x & 7;   // N/128 = 8
  const int m0 = bm << 7, n0 = bn << 7;
  const int wm = (w >> 1) << 6, wn = (w & 1) << 6;

  f32x4 acc[4][4];
#pragma unroll
  for (int i = 0; i < 4; ++i)
#pragma unroll
    for (int j = 0; j < 4; ++j) acc[i][j] = f32x4{0.f, 0.f, 0.f, 0.f};

  // staging: 2 rounds x 256 threads x 16B per tile (A: rows, B: cols of Wt)
  const int srow = tid >> 2, slot = tid & 3;
  const ushort_t* aS0 = A + (size_t)(m0 + srow) * K + slot * 8;
  const ushort_t* aS1 = aS0 + (size_t)64 * K;
  const ushort_t* bS0 = Bt + (size_t)(n0 + srow) * K + slot * 8;
  const ushort_t* bS1 = bS0 + (size_t)64 * K;
  ushort_t* aD0 = As + tid * 8;  ushort_t* aD1 = aD0 + 2048;
  ushort_t* bD0 = Bs + tid * 8;  ushort_t* bD1 = bD0 + 2048;

  const int aoff = (wm + l15) * 32 + lg * 8;   // + i*512 per 16-row frag
  const int boff = (wn + l15) * 32 + lg * 8;

  for (int k0 = 0; k0 < K; k0 += 32) {
    gload_lds16(aS0 + k0, aD0);
    gload_lds16(aS1 + k0, aD1);
    gload_lds16(bS0 + k0, bD0);
    gload_lds16(bS1 + k0, bD1);
    __syncthreads();                      // drains vmcnt, tile visible
    bf16x8 af[4], bfr[4];
#pragma unroll
    for (int i = 0; i < 4; ++i) af[i] = *(const bf16x8*)(As + aoff + i * 512);
#pragma unroll
    for (int j = 0; j < 4; ++j) bfr[j] = *(const bf16x8*)(Bs + boff + j * 512);
#pragma unroll
    for (int i = 0; i < 4; ++i)
#pragma unroll
      for (int j = 0; j < 4; ++j)
        acc[i][j] = __builtin_amdgcn_mfma_f32_16x16x32_bf16(af[i], bfr[j], acc[i][j], 0, 0, 0);
    __syncthreads();                      // all reads done before next stage
  }

  // epilogue; C/D layout: col = lane&15, row = (lane>>4)*4 + r  [m89-verified]
#pragma unroll
  for (int i = 0; i < 4; ++i) {
    const int grow0 = m0 + wm + i * 16 + lg * 4;
#pragma unroll
    for (int j = 0; j < 4; ++j) {
      const int gcol = n0 + wn + j * 16 + l15;
      const float bj = bias[gcol];
#pragma unroll
      for (int r = 0; r < 4; ++r) {
        const float v = acc[i][j][r] + bj;
        const int grow = grow0 + r;
        if constexpr (OUTMODE == 0) {
          ((ushort_t*)Cout)[(size_t)grow * N + gcol] = f2bf(v);
        } else if constexpr (OUTMODE == 1) {
          const int bb = grow >> 11, t = grow & 2047;     // m = b*2048 + t
          const int h = gcol >> 6, d = gcol & 63;         // n = h*64 + d
          ((ushort_t*)Cout)[((size_t)((bb * 16 + h) * 64 + d) << 11) + t] = f2bf(v);
        } else {
          ((float*)Cout)[(size_t)grow * N + gcol] = v;
        }
      }
    }
  }
}

// ---------------------------------------------------------------------------
// Flash attention. 1 wave = 16 q rows of one (b,h); KV block = 64.
// Q/K read from Qp/Kp [B*T][1024] (bf16), V read from Vt [B][H][64][2048].
// K/V fragments come straight from global (L2-resident per (b,h): 512 KB).
// P (16x64) round-trips through a per-wave XOR-swizzled LDS tile.
// ---------------------------------------------------------------------------
__global__ __launch_bounds__(256)
void attn_kernel(const ushort_t* __restrict__ Qp, const ushort_t* __restrict__ Kp,
                 const ushort_t* __restrict__ Vt, ushort_t* __restrict__ AO) {
  __shared__ __attribute__((aligned(16))) ushort_t Pl[4][1024];  // 4 waves x 16x64
  const int tid = threadIdx.x;
  const int l = tid & 63, wid = tid >> 6;
  const int l15 = l & 15, lg = l >> 4;
  const int bh = blockIdx.x >> 5, qb = blockIdx.x & 31;
  const int b = bh >> 4, h = bh & 15;
  const int q0 = qb * 64 + wid * 16;

  ushort_t* myP = &Pl[wid][0];

  // Q fragments (A-operand): row = lane&15, k = (lane>>4)*8 + j
  const ushort_t* qptr = Qp + (size_t)(b * 2048 + q0 + l15) * 1024 + h * 64 + lg * 8;
  const bf16x8 qf0 = ld16(qptr);        // hd 0..31
  const bf16x8 qf1 = ld16(qptr + 32);   // hd 32..63

  const ushort_t* kbase = Kp + (size_t)(b * 2048 + l15) * 1024 + h * 64 + lg * 8;
  const ushort_t* vbase = Vt + ((size_t)((b * 16 + h) * 64 + l15) << 11) + lg * 8;

  f32x4 o[4];
#pragma unroll
  for (int i = 0; i < 4; ++i) o[i] = f32x4{0.f, 0.f, 0.f, 0.f};
  float mrow[4] = {-1e30f, -1e30f, -1e30f, -1e30f};
  float lrow[4] = {0.f, 0.f, 0.f, 0.f};

  const int prd = (l15 * 64 + lg * 8) ^ ((l15 & 7) << 3);  // swizzled P read base

  for (int s0 = 0; s0 < 2048; s0 += 64) {
    // ---- scores = (Q KT) / 8 : 4 col-frags of 16 s-cols ----
    f32x4 sf[4];
#pragma unroll
    for (int cf = 0; cf < 4; ++cf) {
      const ushort_t* kp = kbase + ((size_t)(s0 + cf * 16) << 10);
      const bf16x8 k0 = ld16(kp);
      const bf16x8 k1 = ld16(kp + 32);
      f32x4 a = f32x4{0.f, 0.f, 0.f, 0.f};
      a = __builtin_amdgcn_mfma_f32_16x16x32_bf16(qf0, k0, a, 0, 0, 0);
      a = __builtin_amdgcn_mfma_f32_16x16x32_bf16(qf1, k1, a, 0, 0, 0);
      sf[cf] = a * 0.125f;
    }
    // ---- block row-max across the 16 col-lanes ----
    float bmax[4];
#pragma unroll
    for (int r = 0; r < 4; ++r)
      bmax[r] = fmaxf(fmaxf(sf[0][r], sf[1][r]), fmaxf(sf[2][r], sf[3][r]));
#pragma unroll
    for (int m = 1; m < 16; m <<= 1)
#pragma unroll
      for (int r = 0; r < 4; ++r) bmax[r] = fmaxf(bmax[r], __shfl_xor(bmax[r], m));
    // ---- online-softmax rescale ----
    float sc[4];
#pragma unroll
    for (int r = 0; r < 4; ++r) {
      const float mn = fmaxf(mrow[r], bmax[r]);
      sc[r] = __expf(mrow[r] - mn);
      mrow[r] = mn;
      lrow[r] *= sc[r];
    }
#pragma unroll
    for (int i = 0; i < 4; ++i)
#pragma unroll
      for (int r = 0; r < 4; ++r) o[i][r] *= sc[r];
    // ---- P = exp(s - m), bf16, into swizzled LDS; lsum from rounded P ----
#pragma unroll
    for (int cf = 0; cf < 4; ++cf)
#pragma unroll
      for (int r = 0; r < 4; ++r) {
        const float p = __expf(sf[cf][r] - mrow[r]);
        const ushort_t pb = f2bf(p);
        lrow[r] += bf2f(pb);
        const int row = lg * 4 + r;
        myP[(row * 64 + cf * 16 + l15) ^ ((row & 7) << 3)] = pb;
      }
    asm volatile("s_waitcnt lgkmcnt(0)" ::: "memory");
    __builtin_amdgcn_sched_barrier(0);
    const bf16x8 pf0 = *(const bf16x8*)(myP + prd);          // s 0..31
    const bf16x8 pf1 = *(const bf16x8*)(myP + (prd ^ 32));   // s 32..63
    // ---- O += P V ----
#pragma unroll
    for (int hf = 0; hf < 4; ++hf) {
      const ushort_t* vp = vbase + ((size_t)(hf * 16) << 11) + s0;
      const bf16x8 v0 = ld16(vp);
      const bf16x8 v1 = ld16(vp + 32);
      o[hf] = __builtin_amdgcn_mfma_f32_16x16x32_bf16(pf0, v0, o[hf], 0, 0, 0);
      o[hf] = __builtin_amdgcn_mfma_f32_16x16x32_bf16(pf1, v1, o[hf], 0, 0, 0);
    }
  }
  // ---- finalize: reduce row-sums across col-lanes, normalize, store ----
#pragma unroll
  for (int m = 1; m < 16; m <<= 1)
#pragma unroll
    for (int r = 0; r < 4; ++r) lrow[r] += __shfl_xor(lrow[r], m);
  float linv[4];
#pragma unroll
  for (int r = 0; r < 4; ++r) linv[r] = 1.f / lrow[r];
#pragma unroll
  for (int hf = 0; hf < 4; ++hf)
#pragma unroll
    for (int r = 0; r < 4; ++r)
      AO[(size_t)(b * 2048 + q0 + lg * 4 + r) * 1024 + h * 64 + hf * 16 + l15] =
          f2bf(o[hf][r] * linv[r]);
}

// ---------------------------------------------------------------------------
extern "C" void kernel_launch(void* const* d_in, const int* in_sizes, int n_in,
                              void* d_out, int out_size, void* d_ws, size_t ws_size,
                              hipStream_t stream) {
  (void)in_sizes; (void)n_in; (void)out_size;
  const float* query = (const float*)d_in[0];
  const float* key   = (const float*)d_in[1];
  const float* value = (const float*)d_in[2];
  const float* Wq = (const float*)d_in[3]; const float* bq = (const float*)d_in[4];
  const float* Wk = (const float*)d_in[5]; const float* bk = (const float*)d_in[6];
  const float* Wv = (const float*)d_in[7]; const float* bv = (const float*)d_in[8];
  const float* Wo = (const float*)d_in[9]; const float* bo = (const float*)d_in[10];
  float* out = (float*)d_out;

  constexpr size_t SZX = (size_t)8192 * 1024;   // elements
  constexpr size_t SZW = (size_t)1024 * 1024;
  constexpr size_t NEEDED = (7 * SZX + 4 * SZW) * sizeof(ushort_t);  // 120 MiB
  if (ws_size < NEEDED) return;  // fail loudly (output stays poisoned)

  ushort_t* p = (ushort_t*)d_ws;
  ushort_t* Xq = p;  p += SZX;
  ushort_t* Xk = p;  p += SZX;
  ushort_t* Xv = p;  p += SZX;
  ushort_t* Qp = p;  p += SZX;
  ushort_t* Kp = p;  p += SZX;
  ushort_t* Vt = p;  p += SZX;
  ushort_t* AO = p;  p += SZX;
  ushort_t* Wqt = p; p += SZW;
  ushort_t* Wkt = p; p += SZW;
  ushort_t* Wvt = p; p += SZW;
  ushort_t* Wot = p; p += SZW;

  const int n4 = (int)(SZX / 4);
  cvt_kernel<<<dim3(2048), dim3(256), 0, stream>>>(query, Xq, n4);
  cvt_kernel<<<dim3(2048), dim3(256), 0, stream>>>(key,   Xk, n4);
  cvt_kernel<<<dim3(2048), dim3(256), 0, stream>>>(value, Xv, n4);

  dim3 tg(32, 32), tb(32, 8);
  transpose_cvt_kernel<<<tg, tb, 0, stream>>>(Wq, Wqt);
  transpose_cvt_kernel<<<tg, tb, 0, stream>>>(Wk, Wkt);
  transpose_cvt_kernel<<<tg, tb, 0, stream>>>(Wv, Wvt);
  transpose_cvt_kernel<<<tg, tb, 0, stream>>>(Wo, Wot);

  gemm_kernel<0><<<dim3(512), dim3(256), 0, stream>>>(Xq, Wqt, bq, (void*)Qp);
  gemm_kernel<0><<<dim3(512), dim3(256), 0, stream>>>(Xk, Wkt, bk, (void*)Kp);
  gemm_kernel<1><<<dim3(512), dim3(256), 0, stream>>>(Xv, Wvt, bv, (void*)Vt);

  attn_kernel<<<dim3(2048), dim3(256), 0, stream>>>(Qp, Kp, Vt, AO);

  gemm_kernel<2><<<dim3(512), dim3(256), 0, stream>>>(AO, Wot, bo, (void*)out);
}

// Round 3
// 484.172 us; speedup vs baseline: 1.5224x; 1.5224x over previous
//
#include <hip/hip_runtime.h>
#include <cstdint>
#include <cstddef>

// ---------------------------------------------------------------------------
// Fused attention layer, MI355X/gfx950, round 3 (= round-2 plan, compile fix)
//   Attention: LDS-staged K/V (double-buffered, global_load_lds w/
//   pre-swizzled source), counted vmcnt pipeline, raw s_barrier, 32 q-rows
//   per wave. GEMMs/converts identical to round 1.
// Constants: B=4, T=S=2048, D=1024, H=16, hd=64, M=B*T=8192
// ---------------------------------------------------------------------------

typedef __bf16 bf16x8 __attribute__((ext_vector_type(8)));
typedef float  f32x4  __attribute__((ext_vector_type(4)));
typedef unsigned short ushort_t;

#define DEV __device__ __forceinline__

DEV ushort_t f2bf(float f) {                 // RNE fp32 -> bf16 bits
  unsigned int u = __builtin_bit_cast(unsigned int, f);
  u = u + 0x7fffu + ((u >> 16) & 1u);
  return (ushort_t)(u >> 16);
}
DEV float bf2f(ushort_t b) {
  unsigned int u = ((unsigned int)b) << 16;
  return __builtin_bit_cast(float, u);
}
DEV bf16x8 ld16(const ushort_t* p) { return *(const bf16x8*)p; }

DEV void gload_lds16(const void* g, void* l) {
  // async global->LDS, 16B/lane; LDS dest is wave-uniform-base + lane*16
  __builtin_amdgcn_global_load_lds(
      (__attribute__((address_space(1))) void*)(void*)g,
      (__attribute__((address_space(3))) void*)l, 16, 0, 0);
}

// ---------------------------------------------------------------------------
// fp32 -> bf16 elementwise convert (vectorized)
// ---------------------------------------------------------------------------
__global__ void cvt_kernel(const float* __restrict__ in, ushort_t* __restrict__ out, int n4) {
  int i = blockIdx.x * blockDim.x + threadIdx.x;
  const int stride = gridDim.x * blockDim.x;
  for (; i < n4; i += stride) {
    const float4 v = ((const float4*)in)[i];
    ushort4 o;
    o.x = f2bf(v.x); o.y = f2bf(v.y); o.z = f2bf(v.z); o.w = f2bf(v.w);
    ((ushort4*)out)[i] = o;
  }
}

// ---------------------------------------------------------------------------
// W[k][n] fp32 -> Wt[n][k] bf16 (tiled transpose, 1024x1024)
// ---------------------------------------------------------------------------
__global__ void transpose_cvt_kernel(const float* __restrict__ W, ushort_t* __restrict__ Wt) {
  __shared__ float tile[32][33];
  const int c0 = blockIdx.x * 32, r0 = blockIdx.y * 32;
  const int x = threadIdx.x, y0 = threadIdx.y;
#pragma unroll
  for (int yy = 0; yy < 32; yy += 8)
    tile[y0 + yy][x] = W[(size_t)(r0 + y0 + yy) * 1024 + c0 + x];
  __syncthreads();
#pragma unroll
  for (int yy = 0; yy < 32; yy += 8)
    Wt[(size_t)(c0 + y0 + yy) * 1024 + r0 + x] = f2bf(tile[x][y0 + yy]);
}

// ---------------------------------------------------------------------------
// bf16 GEMM (unchanged from round 1): C[8192][1024] = A @ W + bias, Wt[n][k].
// 128x128 tile, BK=32, 4 waves x (64x64), global_load_lds staging.
// OUTMODE: 0 = bf16 row-major, 1 = bf16 transposed into Vt[b][h][64][2048],
//          2 = fp32 row-major (final output)
// ---------------------------------------------------------------------------
template <int OUTMODE>
__global__ __launch_bounds__(256)
void gemm_kernel(const ushort_t* __restrict__ A, const ushort_t* __restrict__ Bt,
                 const float* __restrict__ bias, void* __restrict__ Cout) {
  constexpr int K = 1024, N = 1024;
  __shared__ __attribute__((aligned(16))) ushort_t As[128 * 32];
  __shared__ __attribute__((aligned(16))) ushort_t Bs[128 * 32];
  const int tid = threadIdx.x;
  const int l = tid & 63, w = tid >> 6;
  const int l15 = l & 15, lg = l >> 4;
  const int bm = blockIdx.x >> 3, bn = blockIdx.x & 7;   // N/128 = 8
  const int m0 = bm << 7, n0 = bn << 7;
  const int wm = (w >> 1) << 6, wn = (w & 1) << 6;

  f32x4 acc[4][4];
#pragma unroll
  for (int i = 0; i < 4; ++i)
#pragma unroll
    for (int j = 0; j < 4; ++j) acc[i][j] = f32x4{0.f, 0.f, 0.f, 0.f};

  const int srow = tid >> 2, slot = tid & 3;
  const ushort_t* aS0 = A + (size_t)(m0 + srow) * K + slot * 8;
  const ushort_t* aS1 = aS0 + (size_t)64 * K;
  const ushort_t* bS0 = Bt + (size_t)(n0 + srow) * K + slot * 8;
  const ushort_t* bS1 = bS0 + (size_t)64 * K;
  ushort_t* aD0 = As + tid * 8;  ushort_t* aD1 = aD0 + 2048;
  ushort_t* bD0 = Bs + tid * 8;  ushort_t* bD1 = bD0 + 2048;

  const int aoff = (wm + l15) * 32 + lg * 8;
  const int boff = (wn + l15) * 32 + lg * 8;

  for (int k0 = 0; k0 < K; k0 += 32) {
    gload_lds16(aS0 + k0, aD0);
    gload_lds16(aS1 + k0, aD1);
    gload_lds16(bS0 + k0, bD0);
    gload_lds16(bS1 + k0, bD1);
    __syncthreads();
    bf16x8 af[4], bfr[4];
#pragma unroll
    for (int i = 0; i < 4; ++i) af[i] = *(const bf16x8*)(As + aoff + i * 512);
#pragma unroll
    for (int j = 0; j < 4; ++j) bfr[j] = *(const bf16x8*)(Bs + boff + j * 512);
#pragma unroll
    for (int i = 0; i < 4; ++i)
#pragma unroll
      for (int j = 0; j < 4; ++j)
        acc[i][j] = __builtin_amdgcn_mfma_f32_16x16x32_bf16(af[i], bfr[j], acc[i][j], 0, 0, 0);
    __syncthreads();
  }

#pragma unroll
  for (int i = 0; i < 4; ++i) {
    const int grow0 = m0 + wm + i * 16 + lg * 4;
#pragma unroll
    for (int j = 0; j < 4; ++j) {
      const int gcol = n0 + wn + j * 16 + l15;
      const float bj = bias[gcol];
#pragma unroll
      for (int r = 0; r < 4; ++r) {
        const float v = acc[i][j][r] + bj;
        const int grow = grow0 + r;
        if constexpr (OUTMODE == 0) {
          ((ushort_t*)Cout)[(size_t)grow * N + gcol] = f2bf(v);
        } else if constexpr (OUTMODE == 1) {
          const int bb = grow >> 11, t = grow & 2047;
          const int h = gcol >> 6, d = gcol & 63;
          ((ushort_t*)Cout)[((size_t)((bb * 16 + h) * 64 + d) << 11) + t] = f2bf(v);
        } else {
          ((float*)Cout)[(size_t)grow * N + gcol] = v;
        }
      }
    }
  }
}

// ---------------------------------------------------------------------------
// Flash attention, round 3.
// Block = 4 waves, Q-tile = 128 rows (32/wave, 2 M-frags). KVBLK = 64.
// K tile [s][hd] and V tile [hd][s] (64x64 bf16, 8 KB) staged to LDS via
// global_load_lds (linear dest, XOR-pre-swizzled SOURCE slot; reads apply the
// same XOR -> conflict-free ds_read_b128). Double-buffered, counted vmcnt(4),
// raw s_barrier (no vmcnt-0 drain). P round-trips per-wave swizzled LDS.
// ---------------------------------------------------------------------------
__global__ __launch_bounds__(256)
void attn_kernel(const ushort_t* __restrict__ Qp, const ushort_t* __restrict__ Kp,
                 const ushort_t* __restrict__ Vt, ushort_t* __restrict__ AO) {
  __shared__ __attribute__((aligned(16))) ushort_t Ks[2][4096];  // [s(64)][hd(64)]
  __shared__ __attribute__((aligned(16))) ushort_t Vs[2][4096];  // [hd(64)][s(64)]
  __shared__ __attribute__((aligned(16))) ushort_t Pl[4][2048];  // per-wave 32x64

  const int tid = threadIdx.x;
  const int l = tid & 63, wid = tid >> 6;
  const int l15 = l & 15, lg = l >> 4;
  const int bh = blockIdx.x >> 4, qt = blockIdx.x & 15;   // grid = 64*16
  const int b = bh >> 4, h = bh & 15;
  const int q0 = qt * 128 + wid * 32;

  // ---- staging addresses (pre-swizzled source slot; LDS dest linear) ----
  const int srow = tid >> 3;                 // 0..31 (row within half-tile)
  const int slot = tid & 7;                  // 16B unit within 128B row
  const int sslot = slot ^ (srow & 7);       // (srow+32)&7 == srow&7, so same
  const ushort_t* kS = Kp + (size_t)(b * 2048 + srow) * 1024 + h * 64 + sslot * 8;
  const ushort_t* vS = Vt + ((size_t)((b * 16 + h) * 64 + srow)) * 2048 + sslot * 8;
  ushort_t* kD = &Ks[0][0] + tid * 8;
  ushort_t* vD = &Vs[0][0] + tid * 8;

#define STAGE(buf, s0)                                                        \
  do {                                                                        \
    gload_lds16(kS + (size_t)(s0) * 1024, kD + (buf) * 4096);                 \
    gload_lds16(kS + (size_t)((s0) + 32) * 1024, kD + (buf) * 4096 + 2048);   \
    gload_lds16(vS + (s0), vD + (buf) * 4096);                                \
    gload_lds16(vS + (size_t)32 * 2048 + (s0), vD + (buf) * 4096 + 2048);     \
  } while (0)

  // ---- Q fragments: 2 M-frags x 2 k-halves ----
  const ushort_t* qptr = Qp + (size_t)(b * 2048 + q0 + l15) * 1024 + h * 64 + lg * 8;
  bf16x8 qf[2][2];
  qf[0][0] = ld16(qptr);              qf[0][1] = ld16(qptr + 32);
  qf[1][0] = ld16(qptr + 16 * 1024);  qf[1][1] = ld16(qptr + 16 * 1024 + 32);

  ushort_t* myP = &Pl[wid][0];

  f32x4 o[2][4];
  float mrow[2][4], lrow[2][4];
#pragma unroll
  for (int mf = 0; mf < 2; ++mf) {
#pragma unroll
    for (int hf = 0; hf < 4; ++hf) o[mf][hf] = f32x4{0.f, 0.f, 0.f, 0.f};
#pragma unroll
    for (int r = 0; r < 4; ++r) { mrow[mf][r] = -1e30f; lrow[mf][r] = 0.f; }
  }

  STAGE(0, 0);                                   // prologue: tile 0

  for (int sb = 0; sb < 32; ++sb) {
    const int cur = sb & 1;
    if (sb < 31) {
      STAGE(cur ^ 1, (sb + 1) * 64);             // prefetch next tile
      asm volatile("s_waitcnt vmcnt(4)" ::: "memory");   // cur tile landed
    } else {
      asm volatile("s_waitcnt vmcnt(0)" ::: "memory");
    }
    __builtin_amdgcn_s_barrier();                // cur tile visible to all

    const ushort_t* kb = &Ks[cur][0];
    const ushort_t* vb = &Vs[cur][0];

    // ---- QK^T ----
    bf16x8 kf[4][2];
#pragma unroll
    for (int cf = 0; cf < 4; ++cf)
#pragma unroll
      for (int kk = 0; kk < 2; ++kk) {
        const int row = cf * 16 + l15;
        kf[cf][kk] = ld16(kb + row * 64 + ((kk * 4 + lg) ^ (row & 7)) * 8);
      }
    f32x4 sf[2][4];
#pragma unroll
    for (int mf = 0; mf < 2; ++mf)
#pragma unroll
      for (int cf = 0; cf < 4; ++cf) {
        f32x4 a = f32x4{0.f, 0.f, 0.f, 0.f};
        a = __builtin_amdgcn_mfma_f32_16x16x32_bf16(qf[mf][0], kf[cf][0], a, 0, 0, 0);
        a = __builtin_amdgcn_mfma_f32_16x16x32_bf16(qf[mf][1], kf[cf][1], a, 0, 0, 0);
        sf[mf][cf] = a * 0.125f;
      }

    // ---- online softmax ----
#pragma unroll
    for (int mf = 0; mf < 2; ++mf) {
      float bmax[4];
#pragma unroll
      for (int r = 0; r < 4; ++r)
        bmax[r] = fmaxf(fmaxf(sf[mf][0][r], sf[mf][1][r]),
                        fmaxf(sf[mf][2][r], sf[mf][3][r]));
#pragma unroll
      for (int m = 1; m < 16; m <<= 1)
#pragma unroll
        for (int r = 0; r < 4; ++r) bmax[r] = fmaxf(bmax[r], __shfl_xor(bmax[r], m));
      float sc[4];
#pragma unroll
      for (int r = 0; r < 4; ++r) {
        const float mn = fmaxf(mrow[mf][r], bmax[r]);
        sc[r] = __expf(mrow[mf][r] - mn);
        mrow[mf][r] = mn;
        lrow[mf][r] *= sc[r];
      }
#pragma unroll
      for (int hf = 0; hf < 4; ++hf)
#pragma unroll
        for (int r = 0; r < 4; ++r) o[mf][hf][r] *= sc[r];
      // P = exp(s - m) -> bf16 -> swizzled per-wave LDS
#pragma unroll
      for (int cf = 0; cf < 4; ++cf)
#pragma unroll
        for (int r = 0; r < 4; ++r) {
          const float p = __expf(sf[mf][cf][r] - mrow[mf][r]);
          const ushort_t pb = f2bf(p);
          lrow[mf][r] += bf2f(pb);
          const int row = mf * 16 + lg * 4 + r;
          myP[row * 64 + ((cf * 16 + l15) ^ ((row & 7) << 3))] = pb;
        }
    }
    asm volatile("s_waitcnt lgkmcnt(0)" ::: "memory");
    __builtin_amdgcn_sched_barrier(0);

    // ---- O += P V ----
    bf16x8 pf[2][2], vf[4][2];
#pragma unroll
    for (int mf = 0; mf < 2; ++mf)
#pragma unroll
      for (int ks = 0; ks < 2; ++ks) {
        const int row = mf * 16 + l15;
        pf[mf][ks] = ld16(myP + row * 64 + ((ks * 4 + lg) ^ (row & 7)) * 8);
      }
#pragma unroll
    for (int hf = 0; hf < 4; ++hf)
#pragma unroll
      for (int ks = 0; ks < 2; ++ks) {
        const int row = hf * 16 + l15;
        vf[hf][ks] = ld16(vb + row * 64 + ((ks * 4 + lg) ^ (row & 7)) * 8);
      }
#pragma unroll
    for (int mf = 0; mf < 2; ++mf)
#pragma unroll
      for (int hf = 0; hf < 4; ++hf) {
        o[mf][hf] = __builtin_amdgcn_mfma_f32_16x16x32_bf16(pf[mf][0], vf[hf][0], o[mf][hf], 0, 0, 0);
        o[mf][hf] = __builtin_amdgcn_mfma_f32_16x16x32_bf16(pf[mf][1], vf[hf][1], o[mf][hf], 0, 0, 0);
      }

    asm volatile("s_waitcnt lgkmcnt(0)" ::: "memory");  // all LDS reads retired
    __builtin_amdgcn_s_barrier();                        // safe to overwrite buf
  }
#undef STAGE

  // ---- finalize ----
#pragma unroll
  for (int mf = 0; mf < 2; ++mf) {
#pragma unroll
    for (int m = 1; m < 16; m <<= 1)
#pragma unroll
      for (int r = 0; r < 4; ++r) lrow[mf][r] += __shfl_xor(lrow[mf][r], m);
    float linv[4];
#pragma unroll
    for (int r = 0; r < 4; ++r) linv[r] = 1.f / lrow[mf][r];
#pragma unroll
    for (int hf = 0; hf < 4; ++hf)
#pragma unroll
      for (int r = 0; r < 4; ++r)
        AO[(size_t)(b * 2048 + q0 + mf * 16 + lg * 4 + r) * 1024 + h * 64 + hf * 16 + l15] =
            f2bf(o[mf][hf][r] * linv[r]);
  }
}

// ---------------------------------------------------------------------------
extern "C" void kernel_launch(void* const* d_in, const int* in_sizes, int n_in,
                              void* d_out, int out_size, void* d_ws, size_t ws_size,
                              hipStream_t stream) {
  (void)in_sizes; (void)n_in; (void)out_size;
  const float* query = (const float*)d_in[0];
  const float* key   = (const float*)d_in[1];
  const float* value = (const float*)d_in[2];
  const float* Wq = (const float*)d_in[3]; const float* bq = (const float*)d_in[4];
  const float* Wk = (const float*)d_in[5]; const float* bk = (const float*)d_in[6];
  const float* Wv = (const float*)d_in[7]; const float* bv = (const float*)d_in[8];
  const float* Wo = (const float*)d_in[9]; const float* bo = (const float*)d_in[10];
  float* out = (float*)d_out;

  constexpr size_t SZX = (size_t)8192 * 1024;   // elements
  constexpr size_t SZW = (size_t)1024 * 1024;
  constexpr size_t NEEDED = (7 * SZX + 4 * SZW) * sizeof(ushort_t);  // 120 MiB
  if (ws_size < NEEDED) return;

  ushort_t* p = (ushort_t*)d_ws;
  ushort_t* Xq = p;  p += SZX;
  ushort_t* Xk = p;  p += SZX;
  ushort_t* Xv = p;  p += SZX;
  ushort_t* Qp = p;  p += SZX;
  ushort_t* Kp = p;  p += SZX;
  ushort_t* Vt = p;  p += SZX;
  ushort_t* AO = p;  p += SZX;
  ushort_t* Wqt = p; p += SZW;
  ushort_t* Wkt = p; p += SZW;
  ushort_t* Wvt = p; p += SZW;
  ushort_t* Wot = p; p += SZW;

  const int n4 = (int)(SZX / 4);
  cvt_kernel<<<dim3(2048), dim3(256), 0, stream>>>(query, Xq, n4);
  cvt_kernel<<<dim3(2048), dim3(256), 0, stream>>>(key,   Xk, n4);
  cvt_kernel<<<dim3(2048), dim3(256), 0, stream>>>(value, Xv, n4);

  dim3 tg(32, 32), tb(32, 8);
  transpose_cvt_kernel<<<tg, tb, 0, stream>>>(Wq, Wqt);
  transpose_cvt_kernel<<<tg, tb, 0, stream>>>(Wk, Wkt);
  transpose_cvt_kernel<<<tg, tb, 0, stream>>>(Wv, Wvt);
  transpose_cvt_kernel<<<tg, tb, 0, stream>>>(Wo, Wot);

  gemm_kernel<0><<<dim3(512), dim3(256), 0, stream>>>(Xq, Wqt, bq, (void*)Qp);
  gemm_kernel<0><<<dim3(512), dim3(256), 0, stream>>>(Xk, Wkt, bk, (void*)Kp);
  gemm_kernel<1><<<dim3(512), dim3(256), 0, stream>>>(Xv, Wvt, bv, (void*)Vt);

  attn_kernel<<<dim3(1024), dim3(256), 0, stream>>>(Qp, Kp, Vt, AO);

  gemm_kernel<2><<<dim3(512), dim3(256), 0, stream>>>(AO, Wot, bo, (void*)out);
}

// Round 4
// 422.527 us; speedup vs baseline: 1.7445x; 1.1459x over previous
//
#include <hip/hip_runtime.h>
#include <cstdint>
#include <cstddef>

// ---------------------------------------------------------------------------
// Fused attention layer, MI355X/gfx950, round 4
//   Round-4 change: attention softmax/P-path rebuilt in registers.
//   Swapped QK^T (S^T = K·Q^T) puts each q-row in one lane -> scalar m/l,
//   cvt_pk_bf16 packing + 2-round shfl butterfly builds the PV B-fragment
//   without the P LDS round-trip. PV swapped (O^T = V^T·P^T). 1/8 folded
//   into Q projection. setprio(1) around MFMA clusters. LDS 48->32 KB.
//   GEMMs/converts otherwise identical to round 3.
// Constants: B=4, T=S=2048, D=1024, H=16, hd=64, M=B*T=8192
// ---------------------------------------------------------------------------

typedef __bf16 bf16x8 __attribute__((ext_vector_type(8)));
typedef float  f32x4  __attribute__((ext_vector_type(4)));
typedef uint32_t u32x4 __attribute__((ext_vector_type(4)));
typedef unsigned short ushort_t;

#define DEV __device__ __forceinline__

DEV ushort_t f2bf(float f) {                 // RNE fp32 -> bf16 bits
  unsigned int u = __builtin_bit_cast(unsigned int, f);
  u = u + 0x7fffu + ((u >> 16) & 1u);
  return (ushort_t)(u >> 16);
}
DEV uint32_t cvt_pk_bf16(float lo, float hi) {   // (hi16|lo16) packed bf16
  uint32_t r;
  asm("v_cvt_pk_bf16_f32 %0, %1, %2" : "=v"(r) : "v"(lo), "v"(hi));
  return r;
}
DEV bf16x8 ld16(const ushort_t* p) { return *(const bf16x8*)p; }

DEV void gload_lds16(const void* g, void* l) {
  // async global->LDS, 16B/lane; LDS dest is wave-uniform-base + lane*16
  __builtin_amdgcn_global_load_lds(
      (__attribute__((address_space(1))) void*)(void*)g,
      (__attribute__((address_space(3))) void*)l, 16, 0, 0);
}

// ---------------------------------------------------------------------------
// fp32 -> bf16 elementwise convert (vectorized)
// ---------------------------------------------------------------------------
__global__ void cvt_kernel(const float* __restrict__ in, ushort_t* __restrict__ out, int n4) {
  int i = blockIdx.x * blockDim.x + threadIdx.x;
  const int stride = gridDim.x * blockDim.x;
  for (; i < n4; i += stride) {
    const float4 v = ((const float4*)in)[i];
    ushort4 o;
    o.x = f2bf(v.x); o.y = f2bf(v.y); o.z = f2bf(v.z); o.w = f2bf(v.w);
    ((ushort4*)out)[i] = o;
  }
}

// ---------------------------------------------------------------------------
// W[k][n] fp32 -> Wt[n][k] bf16 (tiled transpose, 1024x1024)
// ---------------------------------------------------------------------------
__global__ void transpose_cvt_kernel(const float* __restrict__ W, ushort_t* __restrict__ Wt) {
  __shared__ float tile[32][33];
  const int c0 = blockIdx.x * 32, r0 = blockIdx.y * 32;
  const int x = threadIdx.x, y0 = threadIdx.y;
#pragma unroll
  for (int yy = 0; yy < 32; yy += 8)
    tile[y0 + yy][x] = W[(size_t)(r0 + y0 + yy) * 1024 + c0 + x];
  __syncthreads();
#pragma unroll
  for (int yy = 0; yy < 32; yy += 8)
    Wt[(size_t)(c0 + y0 + yy) * 1024 + r0 + x] = f2bf(tile[x][y0 + yy]);
}

// ---------------------------------------------------------------------------
// bf16 GEMM: C[8192][1024] = (A @ W + bias) * scale, W given as Wt[n][k].
// 128x128 tile, BK=32, 4 waves x (64x64), global_load_lds staging.
// OUTMODE: 0 = bf16 row-major, 1 = bf16 transposed into Vt[b][h][64][2048],
//          2 = fp32 row-major (final output)
// ---------------------------------------------------------------------------
template <int OUTMODE>
__global__ __launch_bounds__(256)
void gemm_kernel(const ushort_t* __restrict__ A, const ushort_t* __restrict__ Bt,
                 const float* __restrict__ bias, float scale, void* __restrict__ Cout) {
  constexpr int K = 1024, N = 1024;
  __shared__ __attribute__((aligned(16))) ushort_t As[128 * 32];
  __shared__ __attribute__((aligned(16))) ushort_t Bs[128 * 32];
  const int tid = threadIdx.x;
  const int l = tid & 63, w = tid >> 6;
  const int l15 = l & 15, lg = l >> 4;
  const int bm = blockIdx.x >> 3, bn = blockIdx.x & 7;   // N/128 = 8
  const int m0 = bm << 7, n0 = bn << 7;
  const int wm = (w >> 1) << 6, wn = (w & 1) << 6;

  f32x4 acc[4][4];
#pragma unroll
  for (int i = 0; i < 4; ++i)
#pragma unroll
    for (int j = 0; j < 4; ++j) acc[i][j] = f32x4{0.f, 0.f, 0.f, 0.f};

  const int srow = tid >> 2, slot = tid & 3;
  const ushort_t* aS0 = A + (size_t)(m0 + srow) * K + slot * 8;
  const ushort_t* aS1 = aS0 + (size_t)64 * K;
  const ushort_t* bS0 = Bt + (size_t)(n0 + srow) * K + slot * 8;
  const ushort_t* bS1 = bS0 + (size_t)64 * K;
  ushort_t* aD0 = As + tid * 8;  ushort_t* aD1 = aD0 + 2048;
  ushort_t* bD0 = Bs + tid * 8;  ushort_t* bD1 = bD0 + 2048;

  const int aoff = (wm + l15) * 32 + lg * 8;
  const int boff = (wn + l15) * 32 + lg * 8;

  for (int k0 = 0; k0 < K; k0 += 32) {
    gload_lds16(aS0 + k0, aD0);
    gload_lds16(aS1 + k0, aD1);
    gload_lds16(bS0 + k0, bD0);
    gload_lds16(bS1 + k0, bD1);
    __syncthreads();
    bf16x8 af[4], bfr[4];
#pragma unroll
    for (int i = 0; i < 4; ++i) af[i] = *(const bf16x8*)(As + aoff + i * 512);
#pragma unroll
    for (int j = 0; j < 4; ++j) bfr[j] = *(const bf16x8*)(Bs + boff + j * 512);
#pragma unroll
    for (int i = 0; i < 4; ++i)
#pragma unroll
      for (int j = 0; j < 4; ++j)
        acc[i][j] = __builtin_amdgcn_mfma_f32_16x16x32_bf16(af[i], bfr[j], acc[i][j], 0, 0, 0);
    __syncthreads();
  }

#pragma unroll
  for (int i = 0; i < 4; ++i) {
    const int grow0 = m0 + wm + i * 16 + lg * 4;
#pragma unroll
    for (int j = 0; j < 4; ++j) {
      const int gcol = n0 + wn + j * 16 + l15;
      const float bj = bias[gcol];
#pragma unroll
      for (int r = 0; r < 4; ++r) {
        const float v = (acc[i][j][r] + bj) * scale;
        const int grow = grow0 + r;
        if constexpr (OUTMODE == 0) {
          ((ushort_t*)Cout)[(size_t)grow * N + gcol] = f2bf(v);
        } else if constexpr (OUTMODE == 1) {
          const int bb = grow >> 11, t = grow & 2047;
          const int h = gcol >> 6, d = gcol & 63;
          ((ushort_t*)Cout)[((size_t)((bb * 16 + h) * 64 + d) << 11) + t] = f2bf(v);
        } else {
          ((float*)Cout)[(size_t)grow * N + gcol] = v;
        }
      }
    }
  }
}

// ---------------------------------------------------------------------------
// Flash attention, round 4: in-register softmax + P redistribution.
// Block = 4 waves, Q-tile = 128 rows (32/wave = 2 qh halves of 16). KVBLK=64.
// Swapped QK^T: S^T = mfma(A=K[s][hd], B=Q[q][hd]) -> lane(l15=q) holds
//   P[q][s = cf*16 + lg*4 + r] for cf=0..3, r=0..3 (16 values).
// Pack: u[cf][t'] = cvt_pk(p[cf][2t'], p[cf][2t'+1]) (s-consecutive pairs).
// Butterfly (xor32 then xor16) delivers to lane lg the PV B-frag
//   P[q=l15][s = ks*32 + lg*8 + j], j=0..7. Item math: source (lg'=(a1,a0),
//   cf=(c1,c0), t') -> dest lane (b1=c0, b0=a1), slot (ks=c1, t=2*a0+t').
// PV swapped: O^T = mfma(A=V^T[hd][s], B=P) -> col=l15=q, row=hd.
// ---------------------------------------------------------------------------
__global__ __launch_bounds__(256)
void attn_kernel(const ushort_t* __restrict__ Qp, const ushort_t* __restrict__ Kp,
                 const ushort_t* __restrict__ Vt, ushort_t* __restrict__ AO) {
  __shared__ __attribute__((aligned(16))) ushort_t Ks[2][4096];  // [s(64)][hd(64)]
  __shared__ __attribute__((aligned(16))) ushort_t Vs[2][4096];  // [hd(64)][s(64)]

  const int tid = threadIdx.x;
  const int l = tid & 63, wid = tid >> 6;
  const int l15 = l & 15, lg = l >> 4;
  const int b1 = (lg >> 1) & 1, b0 = lg & 1;
  const bool diag = (b0 == b1);
  const int bh = blockIdx.x >> 4, qt = blockIdx.x & 15;   // grid = 64*16
  const int b = bh >> 4, h = bh & 15;
  const int q0 = qt * 128 + wid * 32;

  // ---- staging addresses (pre-swizzled source slot; LDS dest linear) ----
  const int srow = tid >> 3;                 // 0..31 (row within half-tile)
  const int slot = tid & 7;                  // 16B unit within 128B row
  const int sslot = slot ^ (srow & 7);
  const ushort_t* kS = Kp + (size_t)(b * 2048 + srow) * 1024 + h * 64 + sslot * 8;
  const ushort_t* vS = Vt + ((size_t)((b * 16 + h) * 64 + srow)) * 2048 + sslot * 8;
  ushort_t* kD = &Ks[0][0] + tid * 8;
  ushort_t* vD = &Vs[0][0] + tid * 8;

#define STAGE(buf, s0)                                                        \
  do {                                                                        \
    gload_lds16(kS + (size_t)(s0) * 1024, kD + (buf) * 4096);                 \
    gload_lds16(kS + (size_t)((s0) + 32) * 1024, kD + (buf) * 4096 + 2048);   \
    gload_lds16(vS + (s0), vD + (buf) * 4096);                                \
    gload_lds16(vS + (size_t)32 * 2048 + (s0), vD + (buf) * 4096 + 2048);     \
  } while (0)

  // ---- Q fragments (B-operand: lane l15 = q-row, k = hd contiguous) ----
  // Q was pre-scaled by 1/8 in the projection GEMM.
  const ushort_t* qptr = Qp + (size_t)(b * 2048 + q0 + l15) * 1024 + h * 64 + lg * 8;
  bf16x8 qf[2][2];
  qf[0][0] = ld16(qptr);              qf[0][1] = ld16(qptr + 32);
  qf[1][0] = ld16(qptr + 16 * 1024);  qf[1][1] = ld16(qptr + 16 * 1024 + 32);

  f32x4 o[2][4];                         // [qh][hf]; col=l15=q, row=hd
  float mrun[2] = {-1e30f, -1e30f};
  float lrun[2] = {0.f, 0.f};
#pragma unroll
  for (int qh = 0; qh < 2; ++qh)
#pragma unroll
    for (int hf = 0; hf < 4; ++hf) o[qh][hf] = f32x4{0.f, 0.f, 0.f, 0.f};

  STAGE(0, 0);                                   // prologue: tile 0

  for (int sb = 0; sb < 32; ++sb) {
    const int cur = sb & 1;
    if (sb < 31) {
      STAGE(cur ^ 1, (sb + 1) * 64);             // prefetch next tile
      asm volatile("s_waitcnt vmcnt(4)" ::: "memory");   // cur tile landed
    } else {
      asm volatile("s_waitcnt vmcnt(0)" ::: "memory");
    }
    __builtin_amdgcn_s_barrier();                // cur tile visible to all

    const ushort_t* kb = &Ks[cur][0];
    const ushort_t* vb = &Vs[cur][0];

    // ---- S^T = K·Q^T : A-frag = K rows (lane l15 = s-row) ----
    bf16x8 kf[4][2];
#pragma unroll
    for (int cf = 0; cf < 4; ++cf)
#pragma unroll
      for (int kk = 0; kk < 2; ++kk) {
        const int row = cf * 16 + l15;
        kf[cf][kk] = ld16(kb + row * 64 + ((kk * 4 + lg) ^ (row & 7)) * 8);
      }
    f32x4 st[2][4];                              // [qh][cf]
    __builtin_amdgcn_s_setprio(1);
#pragma unroll
    for (int qh = 0; qh < 2; ++qh)
#pragma unroll
      for (int cf = 0; cf < 4; ++cf) {
        f32x4 a = f32x4{0.f, 0.f, 0.f, 0.f};
        a = __builtin_amdgcn_mfma_f32_16x16x32_bf16(kf[cf][0], qf[qh][0], a, 0, 0, 0);
        a = __builtin_amdgcn_mfma_f32_16x16x32_bf16(kf[cf][1], qf[qh][1], a, 0, 0, 0);
        st[qh][cf] = a;
      }
    __builtin_amdgcn_s_setprio(0);

    // ---- online softmax + in-register P fragment build ----
    bf16x8 pfrag[2][2];                          // [qh][ks]
#pragma unroll
    for (int qh = 0; qh < 2; ++qh) {
      float bm = st[qh][0][0];
#pragma unroll
      for (int cf = 0; cf < 4; ++cf)
#pragma unroll
        for (int r = 0; r < 4; ++r) bm = fmaxf(bm, st[qh][cf][r]);
      bm = fmaxf(bm, __shfl_xor(bm, 16));
      bm = fmaxf(bm, __shfl_xor(bm, 32));
      const float mn = fmaxf(mrun[qh], bm);
      const float sc = __expf(mrun[qh] - mn);
      mrun[qh] = mn;
      float ls = 0.f;
#pragma unroll
      for (int cf = 0; cf < 4; ++cf)
#pragma unroll
        for (int r = 0; r < 4; ++r) {
          const float p = __expf(st[qh][cf][r] - mn);
          st[qh][cf][r] = p;
          ls += p;
        }
      lrun[qh] = lrun[qh] * sc + ls;
#pragma unroll
      for (int hf = 0; hf < 4; ++hf) o[qh][hf] *= sc;

      // pack s-consecutive pairs: u[cf][t'] = P[q][cf*16+lg*4+2t' .. +1]
      uint32_t u[4][2];
#pragma unroll
      for (int cf = 0; cf < 4; ++cf)
#pragma unroll
        for (int tp = 0; tp < 2; ++tp)
          u[cf][tp] = cvt_pk_bf16(st[qh][cf][2 * tp], st[qh][cf][2 * tp + 1]);

      // butterfly round 1 (xor 32, flips b1): exchange items with c0 != b1
      uint32_t r1[4], keep[4];
#pragma unroll
      for (int cfh = 0; cfh < 2; ++cfh)
#pragma unroll
        for (int tp = 0; tp < 2; ++tp) {
          const uint32_t snd = b1 ? u[2 * cfh][tp] : u[2 * cfh + 1][tp];
          r1[cfh * 2 + tp] = (uint32_t)__shfl_xor((int)snd, 32);
          keep[cfh * 2 + tp] = b1 ? u[2 * cfh + 1][tp] : u[2 * cfh][tp];
        }
      // round 2 (xor 16, flips b0): diag lanes send r1, off-diag send keep
      uint32_t w[4], stay[4];
#pragma unroll
      for (int i = 0; i < 4; ++i) {
        const uint32_t z = diag ? r1[i] : keep[i];
        w[i] = (uint32_t)__shfl_xor((int)z, 16);
        stay[i] = diag ? keep[i] : r1[i];
      }
      // assemble B-frag: t-slots {2b0,2b0+1} from stay, others from w
#pragma unroll
      for (int ks = 0; ks < 2; ++ks) {
        u32x4 bb;
        bb.x = b0 ? w[2 * ks]     : stay[2 * ks];
        bb.y = b0 ? w[2 * ks + 1] : stay[2 * ks + 1];
        bb.z = b0 ? stay[2 * ks]     : w[2 * ks];
        bb.w = b0 ? stay[2 * ks + 1] : w[2 * ks + 1];
        pfrag[qh][ks] = __builtin_bit_cast(bf16x8, bb);
      }
    }

    // ---- O^T += V^T·P^T : A-frag = V^T rows (lane l15 = hd-row) ----
    bf16x8 vf[4][2];
#pragma unroll
    for (int hf = 0; hf < 4; ++hf)
#pragma unroll
      for (int ks = 0; ks < 2; ++ks) {
        const int row = hf * 16 + l15;
        vf[hf][ks] = ld16(vb + row * 64 + ((ks * 4 + lg) ^ (row & 7)) * 8);
      }
    __builtin_amdgcn_s_setprio(1);
#pragma unroll
    for (int qh = 0; qh < 2; ++qh)
#pragma unroll
      for (int hf = 0; hf < 4; ++hf) {
        o[qh][hf] = __builtin_amdgcn_mfma_f32_16x16x32_bf16(vf[hf][0], pfrag[qh][0], o[qh][hf], 0, 0, 0);
        o[qh][hf] = __builtin_amdgcn_mfma_f32_16x16x32_bf16(vf[hf][1], pfrag[qh][1], o[qh][hf], 0, 0, 0);
      }
    __builtin_amdgcn_s_setprio(0);

    asm volatile("s_waitcnt lgkmcnt(0)" ::: "memory");  // all LDS reads retired
    __builtin_amdgcn_s_barrier();                        // safe to overwrite buf
  }
#undef STAGE

  // ---- finalize: reduce row-sums across the 4 lg lanes, normalize, store ----
#pragma unroll
  for (int qh = 0; qh < 2; ++qh) {
    float lr = lrun[qh];
    lr += __shfl_xor(lr, 16);
    lr += __shfl_xor(lr, 32);
    const float linv = 1.f / lr;
    const size_t rbase = (size_t)(b * 2048 + q0 + qh * 16 + l15) * 1024 + h * 64 + lg * 4;
#pragma unroll
    for (int hf = 0; hf < 4; ++hf) {
      ushort4 pk;
      pk.x = f2bf(o[qh][hf][0] * linv);
      pk.y = f2bf(o[qh][hf][1] * linv);
      pk.z = f2bf(o[qh][hf][2] * linv);
      pk.w = f2bf(o[qh][hf][3] * linv);
      *(ushort4*)(AO + rbase + hf * 16) = pk;
    }
  }
}

// ---------------------------------------------------------------------------
extern "C" void kernel_launch(void* const* d_in, const int* in_sizes, int n_in,
                              void* d_out, int out_size, void* d_ws, size_t ws_size,
                              hipStream_t stream) {
  (void)in_sizes; (void)n_in; (void)out_size;
  const float* query = (const float*)d_in[0];
  const float* key   = (const float*)d_in[1];
  const float* value = (const float*)d_in[2];
  const float* Wq = (const float*)d_in[3]; const float* bq = (const float*)d_in[4];
  const float* Wk = (const float*)d_in[5]; const float* bk = (const float*)d_in[6];
  const float* Wv = (const float*)d_in[7]; const float* bv = (const float*)d_in[8];
  const float* Wo = (const float*)d_in[9]; const float* bo = (const float*)d_in[10];
  float* out = (float*)d_out;

  constexpr size_t SZX = (size_t)8192 * 1024;   // elements
  constexpr size_t SZW = (size_t)1024 * 1024;
  constexpr size_t NEEDED = (7 * SZX + 4 * SZW) * sizeof(ushort_t);  // 120 MiB
  if (ws_size < NEEDED) return;

  ushort_t* p = (ushort_t*)d_ws;
  ushort_t* Xq = p;  p += SZX;
  ushort_t* Xk = p;  p += SZX;
  ushort_t* Xv = p;  p += SZX;
  ushort_t* Qp = p;  p += SZX;
  ushort_t* Kp = p;  p += SZX;
  ushort_t* Vt = p;  p += SZX;
  ushort_t* AO = p;  p += SZX;
  ushort_t* Wqt = p; p += SZW;
  ushort_t* Wkt = p; p += SZW;
  ushort_t* Wvt = p; p += SZW;
  ushort_t* Wot = p; p += SZW;

  const int n4 = (int)(SZX / 4);
  cvt_kernel<<<dim3(2048), dim3(256), 0, stream>>>(query, Xq, n4);
  cvt_kernel<<<dim3(2048), dim3(256), 0, stream>>>(key,   Xk, n4);
  cvt_kernel<<<dim3(2048), dim3(256), 0, stream>>>(value, Xv, n4);

  dim3 tg(32, 32), tb(32, 8);
  transpose_cvt_kernel<<<tg, tb, 0, stream>>>(Wq, Wqt);
  transpose_cvt_kernel<<<tg, tb, 0, stream>>>(Wk, Wkt);
  transpose_cvt_kernel<<<tg, tb, 0, stream>>>(Wv, Wvt);
  transpose_cvt_kernel<<<tg, tb, 0, stream>>>(Wo, Wot);

  // Q projection pre-scaled by 1/sqrt(hd) = 1/8 (exact in bf16)
  gemm_kernel<0><<<dim3(512), dim3(256), 0, stream>>>(Xq, Wqt, bq, 0.125f, (void*)Qp);
  gemm_kernel<0><<<dim3(512), dim3(256), 0, stream>>>(Xk, Wkt, bk, 1.0f,   (void*)Kp);
  gemm_kernel<1><<<dim3(512), dim3(256), 0, stream>>>(Xv, Wvt, bv, 1.0f,   (void*)Vt);

  attn_kernel<<<dim3(1024), dim3(256), 0, stream>>>(Qp, Kp, Vt, AO);

  gemm_kernel<2><<<dim3(512), dim3(256), 0, stream>>>(AO, Wot, bo, 1.0f, (void*)out);
}